// Round 13
// baseline (336.532 us; speedup 1.0000x reference)
//
#include <hip/hip_runtime.h>

typedef __attribute__((ext_vector_type(8))) short bf16x8;
typedef __attribute__((ext_vector_type(4))) float f32x4;
typedef __attribute__((ext_vector_type(8))) unsigned short u16x8;

__device__ __forceinline__ unsigned short bf16u(float x) {
    unsigned int u = __builtin_bit_cast(unsigned int, x);
    unsigned int r = (u + 0x7fffu + ((u >> 16) & 1u)) >> 16;
    return (unsigned short)r;
}
__device__ __forceinline__ float bf2f(unsigned short u) {
    return __builtin_bit_cast(float, (unsigned int)u << 16);
}
__device__ __forceinline__ void gll16(const void* g, void* l) {
    __builtin_amdgcn_global_load_lds((const __attribute__((address_space(1))) void*)g,
                                     (__attribute__((address_space(3))) void*)l, 16, 0, 0);
}

// ---------------------------------------------------------------------------
// Setup: blocks [0,335) zero h_bf/t_bf borders + sum buffers;
//        blocks [335,411) weight-norm head (64) + skip (12);
//        blocks [411,427) tail weight-norm + fragment repack (16 mo rows).
// ---------------------------------------------------------------------------
__global__ __launch_bounds__(256) void setup_kernel(
    unsigned short* __restrict__ hbf, unsigned short* __restrict__ tbf,
    float* __restrict__ sums,
    const float* __restrict__ hv, const float* __restrict__ hg, float* __restrict__ hw,
    const float* __restrict__ kv, const float* __restrict__ kg, float* __restrict__ kw,
    const float* __restrict__ tv, const float* __restrict__ tg,
    unsigned short* __restrict__ wqt) {
    int blk = blockIdx.x;
    int tid = threadIdx.x;
    if (blk < 335) {
        int i = blk * 256 + tid;
        u16x8 z8 = {0, 0, 0, 0, 0, 0, 0, 0};
        if (i < 16640) {          // h_bf borders: 16 slabs * 260 * 4 chunks
            int chv = i & 3, pb = i >> 2, pos = pb % 260, bc = pb / 260;
            int y, x;
            if (pos < 66) { y = 0; x = pos; }
            else if (pos < 132) { y = 65; x = pos - 66; }
            else if (pos < 196) { y = pos - 131; x = 0; }
            else { y = pos - 195; x = 65; }
            *(u16x8*)&hbf[((size_t)bc * 4356 + y * 66 + x) * 32 + chv * 8] = z8;
        } else if (i < 83200) {   // t_bf borders: 64 slabs * 260 * 4 chunks
            int j = i - 16640;
            int chv = j & 3, pb = j >> 2, pos = pb % 260, bc = pb / 260;
            int y, x;
            if (pos < 66) { y = 0; x = pos; }
            else if (pos < 132) { y = 65; x = pos - 66; }
            else if (pos < 196) { y = pos - 131; x = 0; }
            else { y = pos - 195; x = 65; }
            *(u16x8*)&tbf[((size_t)bc * 4356 + y * 66 + x) * 32 + chv * 8] = z8;
        } else {
            int k = i - 83200;    // < 2560
            f32x4 z4 = {0.f, 0.f, 0.f, 0.f};
            ((f32x4*)sums)[k] = z4;
        }
        return;
    }
    __shared__ float srow[576];
    __shared__ float red[4];
    __shared__ float s_sc;
    if (blk < 411) {
        // weight norm (head / skip)
        int b2 = blk - 335;
        const float *v, *g;
        float* outw;
        int len, row;
        if (b2 < 64) { v = hv; g = hg; outw = hw; len = 27; row = b2; }
        else         { v = kv; g = kg; outw = kw; len = 75; row = b2 - 64; }
        const float* vr = v + (size_t)row * len;
        float ss = 0.f;
        for (int i = tid; i < len; i += 256) { float a = vr[i]; ss += a * a; }
        for (int o = 32; o > 0; o >>= 1) ss += __shfl_down(ss, o);
        if ((tid & 63) == 0) red[tid >> 6] = ss;
        __syncthreads();
        if (tid == 0) s_sc = g[row] / sqrtf(red[0] + red[1] + red[2] + red[3]);
        __syncthreads();
        float sc = s_sc;
        float* orow = outw + (size_t)row * len;
        for (int i = tid; i < len; i += 256) orow[i] = vr[i] * sc;
        return;
    }
    // tail repack: one block per mo
    int mo = blk - 411;
    if (mo < 12) {
        for (int i = tid; i < 576; i += 256) srow[i] = tv[mo * 576 + i];
        __syncthreads();
        float ss = 0.f;
        for (int i = tid; i < 576; i += 256) { float a = srow[i]; ss += a * a; }
        for (int o = 32; o > 0; o >>= 1) ss += __shfl_down(ss, o);
        if ((tid & 63) == 0) red[tid >> 6] = ss;
        __syncthreads();
        if (tid == 0) s_sc = tg[mo] / sqrtf(red[0] + red[1] + red[2] + red[3]);
        __syncthreads();
        float sc = s_sc;
        for (int ch = tid; ch < 72; ch += 256) {
            int kg = ch & 3, c2 = ch >> 2;
            int t = c2 % 9, kc = c2 / 9;
            u16x8 pk;
#pragma unroll
            for (int kj = 0; kj < 8; ++kj) {
                int ic = kc * 32 + kg * 8 + kj;
                pk[kj] = bf16u(srow[ic * 9 + t] * sc);
            }
            *(u16x8*)&wqt[(size_t)((kc * 9 + t) * 4 + kg) * 128 + mo * 8] = pk;
        }
    } else {
        u16x8 z = {0, 0, 0, 0, 0, 0, 0, 0};
        for (int ch = tid; ch < 72; ch += 256) {
            int kg = ch & 3, c2 = ch >> 2;
            int t = c2 % 9, kc = c2 / 9;
            *(u16x8*)&wqt[(size_t)((kc * 9 + t) * 4 + kg) * 128 + mo * 8] = z;
        }
    }
}

// ---------------------------------------------------------------------------
// combine_v4: wn-fused per-sample weight combine + routing softmax.
// One block = GOC output channels x ONE sample. grid (OC/GOC, 8).
// wq layout [b][ot][kc][t][kg][mo(2^LGMO)][kj(8)].
// ---------------------------------------------------------------------------
template <int IC, int GOC, int LGMO>
__global__ __launch_bounds__(256) void combine_v4(
    const float* __restrict__ v, const float* __restrict__ g,
    const float* __restrict__ msum, const float* __restrict__ mw,
    const float* __restrict__ mb, float* __restrict__ s_out,
    unsigned short* __restrict__ wq, int D, int OC) {
    constexpr int ROWF = IC * 9;
    constexpr int KCh = IC / 32;
    constexpr int ROWS2 = 2 * GOC;
    constexpr int TOTC = GOC * KCh * 9 * 4;
    constexpr int TPR = 256 / ROWS2;
    __shared__ float lv[ROWS2 * ROWF];
    __shared__ float lg[8], sv8[8], scr[ROWS2], sw[ROWS2];
    int tid = threadIdx.x;
    int ocg = blockIdx.x * GOC;
    int b = blockIdx.y;
    for (int i = tid; i < ROWS2 * ROWF; i += 256) {
        int r = i / ROWF, jj = i - r * ROWF;
        int oc_r = (r / GOC) * OC + ocg + (r % GOC);
        lv[i] = v[(size_t)oc_r * ROWF + jj];
    }
    {
        int j = tid >> 5, l32 = tid & 31;
        float part = 0.f;
        for (int i = l32; i < IC; i += 32) part += msum[b * IC + i] * mw[j * IC + i];
        for (int m = 16; m > 0; m >>= 1) part += __shfl_xor(part, m);
        if (l32 == 0) lg[j] = part * (1.f / 4096.f) + mb[j];
    }
    __syncthreads();
    {
        int r = tid / TPR, lr = tid % TPR;
        float ss = 0.f;
        for (int i = lr; i < ROWF; i += TPR) { float a = lv[r * ROWF + i]; ss += a * a; }
#pragma unroll
        for (int m = TPR >> 1; m > 0; m >>= 1) ss += __shfl_xor(ss, m);
        if (lr == 0) {
            int oc_r = (r / GOC) * OC + ocg + (r % GOC);
            scr[r] = g[oc_r] / sqrtf(ss);
        }
    }
    if (tid < 8) {
        int gg = tid >> 2, c = tid & 3;
        float l0 = lg[c], l1 = lg[4 + c];
        float m = fmaxf(l0, l1);
        float e0 = __expf(l0 - m), e1 = __expf(l1 - m);
        float val = ((gg == 0) ? e0 : e1) / (e0 + e1);
        sv8[tid] = val;
        if (blockIdx.x == 0) s_out[b * 8 + tid] = val;
    }
    __syncthreads();
    if (tid < ROWS2) {
        int r = tid;
        int oc = ocg + (r % GOC);
        int cd = oc / D;
        float s = (r < GOC) ? sv8[cd] : sv8[4 + cd];
        sw[r] = s * scr[r];
    }
    __syncthreads();
    for (int ci = tid; ci < TOTC; ci += 256) {
        int ml = ci % GOC;
        int c = ci / GOC;
        int kg = c & 3, c2 = c >> 2;
        int t = c2 % 9, kc = c2 / 9;
        int oc = ocg + ml;
        float s0 = sw[ml], s1 = sw[GOC + ml];
        const float* p0 = &lv[(size_t)ml * ROWF];
        const float* p1 = &lv[(size_t)(GOC + ml) * ROWF];
        u16x8 pk;
#pragma unroll
        for (int kj = 0; kj < 8; ++kj) {
            int ic9 = (kc * 32 + kg * 8 + kj) * 9 + t;
            pk[kj] = bf16u(s0 * p0[ic9] + s1 * p1[ic9]);
        }
        size_t w_off = ((((size_t)(b * (OC >> LGMO) + (oc >> LGMO)) * KCh + kc) * 9 + t) * 4 + kg)
                           * ((1 << LGMO) * 8) + (size_t)(oc & ((1 << LGMO) - 1)) * 8;
        *(u16x8*)&wq[w_off] = pk;
    }
}

// ---------------------------------------------------------------------------
// MFMA implicit-GEMM 3x3 conv. Input [b][IC/32][66][66][32] bf16 slabs.
// S double-buffered; A-frags global->VGPR 2-tap ring; NF-pair shuffle epilogue.
// KCH==2: both kc tiles staged upfront, ONE barrier, no mid-loop drains.
// grid = (b, strip, ot).
// ---------------------------------------------------------------------------
template <int IC, int OC, int MT, int WM, int WN, int NR,
          bool RELU, bool RES, bool WF32, bool WBF, int OCR, bool DYNB, int MINW>
__global__ __launch_bounds__(WM * WN * 64, MINW)
void conv_mfma(
    const unsigned short* __restrict__ in_bf,
    const unsigned short* __restrict__ wq,
    const float* __restrict__ bias_raw, const float* __restrict__ s8, int lgD,
    float* __restrict__ out,
    unsigned short* __restrict__ out_bf, float* __restrict__ msum, long wstride) {
    constexpr int THREADS = WM * WN * 64;
    constexpr int KCH = IC / 32;
    constexpr int NRH = NR + 2;
    constexpr int NT = NR * 64;
    constexpr int NF = (NT / 16) / WN;
    constexpr int MW = MT / (16 * WM);
    constexpr int WELEM = 9 * 32 * MT;
    constexpr int SELEM = NRH * 66 * 32;
    constexpr int SCH = SELEM / 8;
    constexpr int OCB = OCR / 32;

    __shared__ __align__(16) unsigned short S[2][SELEM];
    __shared__ float MRED[WN][MT];

    const int b = blockIdx.x, ot = blockIdx.z;
    const int y0 = blockIdx.y * NR;
    const int tid = threadIdx.x;
    const int lane = tid & 63;
    const int wid = tid >> 6;
    const int wm = wid / WN, wn = wid % WN;
    const int l15 = lane & 15, lk = lane >> 4;
    const int wmo = wm * (MT / WM);
    const int wno = wn * (NT / WN);

    f32x4 acc[MW][NF];
#pragma unroll
    for (int mf = 0; mf < MW; ++mf)
#pragma unroll
        for (int nf = 0; nf < NF; ++nf)
#pragma unroll
            for (int q = 0; q < 4; ++q) acc[mf][nf][q] = 0.f;

    const unsigned short* inb = in_bf + (size_t)b * KCH * (4356 * 32);
    const unsigned short* wqb = wq + (size_t)b * wstride + (size_t)ot * (KCH * WELEM);
    const unsigned short* wqa = wqb + (size_t)lk * (MT * 8) + (size_t)(wmo + l15) * 8;

    auto STAGE_S = [&](int kc, int buf) {
        const unsigned short* sb = inb + (size_t)kc * (4356 * 32);
        for (int i = tid; i < SCH; i += THREADS) {
            int Lz = i ^ ((i >> 3) & 7);
            int lk2 = Lz & 3, cr = Lz >> 2;
            int col = cr % 66, row = cr / 66;
            gll16(sb + ((size_t)(y0 + row) * 66 + col) * 32 + lk2 * 8,
                  (char*)S[buf] + i * 16);
        }
    };

    bf16x8 aT[2][MW];
#pragma unroll
    for (int mf = 0; mf < MW; ++mf) {
        aT[0][mf] = *(const bf16x8*)(wqa + mf * (16 * 8));
        aT[1][mf] = *(const bf16x8*)(wqa + (4 * MT * 8) + mf * (16 * 8));
    }
    if constexpr (KCH == 2) {
        STAGE_S(0, 0);
        STAGE_S(1, 1);
    } else {
        STAGE_S(0, 0);
    }
    __syncthreads();
#pragma unroll
    for (int kc = 0; kc < KCH; ++kc) {
        if constexpr (KCH != 2) {
            if (kc + 1 < KCH) STAGE_S(kc + 1, (kc + 1) & 1);
        }
        const unsigned short* Sb = S[kc & 1];
#pragma unroll
        for (int t = 0; t < 9; ++t) {
            const int gt = kc * 9 + t;
            const int pp = gt & 1;
            const int dy = t / 3, dx = t % 3;
#pragma unroll
            for (int nf = 0; nf < NF; ++nf) {
                int n = wno + nf * 16 + l15;
                int r = n >> 6, c = n & 63;
                int L = ((r + dy) * 66 + (c + dx)) * 4 + lk;
                int P = L ^ ((L >> 3) & 7);
                bf16x8 bv = *(const bf16x8*)((const char*)Sb + P * 16);
#pragma unroll
                for (int mf = 0; mf < MW; ++mf)
                    acc[mf][nf] = __builtin_amdgcn_mfma_f32_16x16x32_bf16(aT[pp][mf], bv, acc[mf][nf], 0, 0, 0);
            }
            if (gt + 2 < KCH * 9) {
                const int ngt = gt + 2;
                const int nkc = ngt / 9, nt2 = ngt % 9;
#pragma unroll
                for (int mf = 0; mf < MW; ++mf)
                    aT[pp][mf] = *(const bf16x8*)(wqa + (size_t)nkc * WELEM + nt2 * (4 * MT * 8) + mf * (16 * 8));
            }
        }
        if constexpr (KCH != 2) __syncthreads();
    }

    if constexpr (WBF) {
        const int ch = lk >> 1;
        const bool oddlk = (lk & 1);
#pragma unroll
        for (int mf = 0; mf < MW; ++mf) {
            int ocb = ot * MT + wmo + mf * 16 + lk * 4;
            float bvv[4];
#pragma unroll
            for (int q = 0; q < 4; ++q) {
                int oc = ocb + q;
                if (DYNB) {
                    int cc = oc >> lgD;
                    bvv[q] = s8[b * 8 + cc] * bias_raw[oc] + s8[b * 8 + 4 + cc] * bias_raw[OCR + oc];
                } else {
                    bvv[q] = bias_raw[oc];
                }
            }
            int occ = ot * MT + wmo + mf * 16 + ch * 8;
            float msr8[8];
#pragma unroll
            for (int j = 0; j < 8; ++j) msr8[j] = 0.f;
#pragma unroll
            for (int nfp = 0; nfp < NF; nfp += 2) {
                float r0[2][4], pr[2][4];
#pragma unroll
                for (int h = 0; h < 2; ++h)
#pragma unroll
                    for (int q = 0; q < 4; ++q) {
                        float v = acc[mf][nfp + h][q] + bvv[q];
                        if (RELU) v = fmaxf(v, 0.f);
                        r0[h][q] = v;
                    }
#pragma unroll
                for (int h = 0; h < 2; ++h)
#pragma unroll
                    for (int q = 0; q < 4; ++q) pr[h][q] = __shfl_xor(r0[h][q], 16);
                float v8[8];
#pragma unroll
                for (int q = 0; q < 4; ++q) {
                    float own = oddlk ? r0[1][q] : r0[0][q];
                    float oth = oddlk ? pr[1][q] : pr[0][q];
                    v8[q]     = oddlk ? oth : own;
                    v8[4 + q] = oddlk ? own : oth;
                }
                int mynf = nfp + (lk & 1);
                int n = wno + mynf * 16 + l15;
                int y = y0 + (n >> 6), x = n & 63;
                size_t addr = ((((size_t)b * OCB + (occ >> 5)) * 66 + (y + 1)) * 66 + (x + 1)) * 32
                              + (occ & 31);
                if (RES) {
                    u16x8 rv = *(const u16x8*)&out_bf[addr];
#pragma unroll
                    for (int j = 0; j < 8; ++j) v8[j] += bf2f(rv[j]);
                }
                u16x8 pk;
#pragma unroll
                for (int j = 0; j < 8; ++j) pk[j] = bf16u(v8[j]);
                *(u16x8*)&out_bf[addr] = pk;
#pragma unroll
                for (int j = 0; j < 8; ++j) msr8[j] += v8[j];
            }
            if (msum) {
#pragma unroll
                for (int j = 0; j < 8; ++j) {
                    float t = msr8[j];
                    t += __shfl_xor(t, 1);
                    t += __shfl_xor(t, 2);
                    t += __shfl_xor(t, 4);
                    t += __shfl_xor(t, 8);
                    t += __shfl_xor(t, 16);
                    msr8[j] = t;
                }
                if ((lane & 31) == 0) {
#pragma unroll
                    for (int j = 0; j < 8; ++j)
                        MRED[wn][wmo + mf * 16 + ch * 8 + j] = msr8[j];
                }
            }
        }
        if (msum) {
            __syncthreads();
            if (tid < MT) {
                float tot = 0.f;
#pragma unroll
                for (int w2 = 0; w2 < WN; ++w2) tot += MRED[w2][tid];
                atomicAdd(&msum[b * OCR + ot * MT + tid], tot);
            }
        }
    }
    if constexpr (WF32) {
#pragma unroll
        for (int mf = 0; mf < MW; ++mf) {
            int ocb = ot * MT + wmo + mf * 16 + lk * 4;
#pragma unroll
            for (int nf = 0; nf < NF; ++nf) {
                int n = wno + nf * 16 + l15;
                int y = y0 + (n >> 6), x = n & 63;
#pragma unroll
                for (int q = 0; q < 4; ++q) {
                    int oc = ocb + q;
                    if (oc < OCR) {
                        float v = acc[mf][nf][q] + bias_raw[oc];
                        out[(((size_t)b * OCR + oc) * 64 + y) * 64 + x] = v;
                    }
                }
            }
        }
    }
}

// ---------------------------------------------------------------------------
// Head conv 3->64 direct fp32; OCT=8, 256 blocks (1/CU). Writes h_bf + hsum0.
// ---------------------------------------------------------------------------
__global__ __launch_bounds__(256) void head_conv(
    const float* __restrict__ in, const float* __restrict__ w,
    const float* __restrict__ bias,
    unsigned short* __restrict__ out_bf, float* __restrict__ hsum0) {
    constexpr int OCT = 8, IC = 3;
    __shared__ float s_in[34 * 34];
    __shared__ float s_w[OCT * 9];
    __shared__ float wred[4][OCT];
    int b = blockIdx.z;
    int ocBase = blockIdx.y * OCT;
    int ty0 = (blockIdx.x >> 1) * 32;
    int tx0 = (blockIdx.x & 1) * 32;
    int tid = threadIdx.x;
    int lane = tid & 63, wid = tid >> 6;
    int tx = tid & 15, ty = tid >> 4;

    float acc[OCT][4];
#pragma unroll
    for (int oc = 0; oc < OCT; ++oc)
#pragma unroll
        for (int p = 0; p < 4; ++p) acc[oc][p] = 0.f;

    const float* inb = in + (size_t)b * IC * 4096;
    for (int ic = 0; ic < IC; ++ic) {
        const float* src = inb + (size_t)ic * 4096;
        for (int i = tid; i < 34 * 34; i += 256) {
            int r = i / 34, cc = i % 34;
            int gy = ty0 + r - 1, gx = tx0 + cc - 1;
            float val = 0.f;
            if (gy >= 0 && gy < 64 && gx >= 0 && gx < 64) val = src[gy * 64 + gx] - 0.5f;
            s_in[i] = val;
        }
        for (int i = tid; i < OCT * 9; i += 256) {
            int oc = i / 9, t = i % 9;
            s_w[i] = w[((size_t)(ocBase + oc) * IC + ic) * 9 + t];
        }
        __syncthreads();
        float v[4][4];
#pragma unroll
        for (int r = 0; r < 4; ++r)
#pragma unroll
            for (int cc = 0; cc < 4; ++cc) v[r][cc] = s_in[(2 * ty + r) * 34 + (2 * tx + cc)];
#pragma unroll
        for (int oc = 0; oc < OCT; ++oc) {
#pragma unroll
            for (int ky = 0; ky < 3; ++ky)
#pragma unroll
                for (int kx = 0; kx < 3; ++kx) {
                    float wv = s_w[oc * 9 + ky * 3 + kx];
                    acc[oc][0] += wv * v[ky][kx];
                    acc[oc][1] += wv * v[ky][kx + 1];
                    acc[oc][2] += wv * v[ky + 1][kx];
                    acc[oc][3] += wv * v[ky + 1][kx + 1];
                }
        }
        __syncthreads();
    }
    int py = ty0 + 2 * ty, px = tx0 + 2 * tx;
#pragma unroll
    for (int oc = 0; oc < OCT; ++oc) {
        int og = ocBase + oc;
        float bv = bias[og];
        float osum = 0.f;
#pragma unroll
        for (int p = 0; p < 4; ++p) {
            int dy = p >> 1, dx = p & 1;
            float val = acc[oc][p] + bv;
            osum += val;
            out_bf[((size_t)(b * 2 + (og >> 5)) * 4356 + (py + dy + 1) * 66 + (px + dx + 1)) * 32
                   + (og & 31)] = bf16u(val);
        }
        for (int m = 1; m < 64; m <<= 1) osum += __shfl_xor(osum, m);
        if (lane == 0) wred[wid][oc] = osum;
    }
    __syncthreads();
    if (tid < OCT)
        atomicAdd(&hsum0[b * 64 + ocBase + tid],
                  wred[0][tid] + wred[1][tid] + wred[2][tid] + wred[3][tid]);
}

// ---------------------------------------------------------------------------
// Pixel shuffle + fused 5x5 skip conv + IMAGE_MEAN. out [8,3,128,128]
// ---------------------------------------------------------------------------
__global__ __launch_bounds__(256) void shuffle_skip(
    const float* __restrict__ body, const float* __restrict__ x,
    const float* __restrict__ skw, const float* __restrict__ skb,
    float* __restrict__ out) {
    __shared__ float w[900];
    __shared__ float bb[12];
    int tid = threadIdx.x;
    for (int i = tid; i < 900; i += 256) w[i] = skw[i];
    if (tid < 12) bb[tid] = skb[tid];
    __syncthreads();
    int idx = blockIdx.x * 256 + tid;
    int ox = idx & 127;
    int oy = (idx >> 7) & 127;
    int v = idx >> 14;
    int c = v % 3;
    int b = v / 3;
    int rx = ox & 1, ry = oy & 1;
    int xx = ox >> 1, yy = oy >> 1;
    int ch = c * 4 + ry * 2 + rx;
    float acc = bb[ch];
    for (int ic = 0; ic < 3; ++ic)
        for (int ky = 0; ky < 5; ++ky) {
            int gy = yy + ky - 2;
            if (gy < 0 || gy >= 64) continue;
            for (int kx = 0; kx < 5; ++kx) {
                int gx = xx + kx - 2;
                if (gx < 0 || gx >= 64) continue;
                acc += w[((ch * 3 + ic) * 5 + ky) * 5 + kx] *
                       (x[((size_t)(b * 3 + ic) * 64 + gy) * 64 + gx] - 0.5f);
            }
        }
    size_t src = (((size_t)b * 12 + ch) * 64 + yy) * 64 + xx;
    out[idx] = body[src] + acc + 0.5f;
}

// ---------------------------------------------------------------------------
extern "C" void kernel_launch(void* const* d_in, const int* in_sizes, int n_in,
                              void* d_out, int out_size, void* d_ws, size_t ws_size,
                              hipStream_t stream) {
    const float* x      = (const float*)d_in[0];
    const float* head_v = (const float*)d_in[1];
    const float* head_g = (const float*)d_in[2];
    const float* head_b = (const float*)d_in[3];
    const float* b1_v   = (const float*)d_in[4];
    const float* b1_g   = (const float*)d_in[5];
    const float* b1_b   = (const float*)d_in[6];
    const float* b1_mw  = (const float*)d_in[7];
    const float* b1_mb  = (const float*)d_in[8];
    const float* b2_v   = (const float*)d_in[9];
    const float* b2_g   = (const float*)d_in[10];
    const float* b2_b   = (const float*)d_in[11];
    const float* b2_mw  = (const float*)d_in[12];
    const float* b2_mb  = (const float*)d_in[13];
    const float* tail_v = (const float*)d_in[14];
    const float* tail_g = (const float*)d_in[15];
    const float* tail_b = (const float*)d_in[16];
    const float* skip_v = (const float*)d_in[17];
    const float* skip_g = (const float*)d_in[18];
    const float* skip_b = (const float*)d_in[19];

    float* ws = (float*)d_ws;
    size_t off = 0;
    auto alloc = [&](size_t n) { float* p = ws + off; off += (n + 3) & ~(size_t)3; return p; };
    float* head_w = alloc(64 * 27);
    float* skip_w = alloc(12 * 75);
    float* sums   = alloc(10240);   // hsum[4] @ l*512 ; tsum[4] @ 2048 + l*2048
    float* sbuf   = alloc(64);
    float* body   = alloc((size_t)8 * 12 * 4096);
    unsigned short* wq1  = (unsigned short*)alloc((size_t)8 * 256 * 576 / 2);
    unsigned short* wq2  = (unsigned short*)alloc((size_t)8 * 64 * 2304 / 2);
    unsigned short* wqt  = (unsigned short*)alloc(9216 / 2);
    unsigned short* h_bf = (unsigned short*)alloc((size_t)8 * 2 * 4356 * 32 / 2);
    unsigned short* t_bf = (unsigned short*)alloc((size_t)8 * 8 * 4356 * 32 / 2);
    (void)ws_size; (void)in_sizes; (void)n_in; (void)out_size;

    auto hsum = [&](int l) { return sums + l * 512; };
    auto tsum = [&](int l) { return sums + 2048 + l * 2048; };

    setup_kernel<<<427, 256, 0, stream>>>(h_bf, t_bf, sums, head_v, head_g, head_w,
                                          skip_v, skip_g, skip_w, tail_v, tail_g, wqt);
    head_conv<<<dim3(4, 8, 8), 256, 0, stream>>>(x, head_w, head_b, h_bf, hsum(0));

    for (int l = 0; l < 4; ++l) {
        // dyn conv 1: 64 -> 256, relu. WM=1/WN=4 (MW=4): B-frag feeds 4 MFMAs.
        combine_v4<64, 4, 6><<<dim3(64, 8), 256, 0, stream>>>(
            b1_v + (size_t)l * 512 * 576, b1_g + (size_t)l * 512, hsum(l),
            b1_mw + (size_t)l * 8 * 64, b1_mb + l * 8, sbuf, wq1, 64, 256);
        conv_mfma<64, 256, 64, 1, 4, 2, true, false, false, true, 256, true, 4>
            <<<dim3(8, 32, 4), 256, 0, stream>>>(h_bf, wq1, b1_b + (size_t)l * 512, sbuf, 6,
                                                 nullptr, t_bf, tsum(l), 147456);
        // dyn conv 2: 256 -> 64, bf16 in-place residual. 256thr, 512 blocks.
        combine_v4<256, 2, 6><<<dim3(32, 8), 256, 0, stream>>>(
            b2_v + (size_t)l * 128 * 2304, b2_g + (size_t)l * 128, tsum(l),
            b2_mw + (size_t)l * 8 * 256, b2_mb + l * 8, sbuf, wq2, 16, 64);
        conv_mfma<256, 64, 64, 2, 2, 1, false, true, false, true, 64, true, 4>
            <<<dim3(8, 64, 1), 256, 0, stream>>>(t_bf, wq2, b2_b + (size_t)l * 128, sbuf, 4,
                                                 nullptr, h_bf, (l < 3) ? hsum(l + 1) : nullptr,
                                                 147456);
    }

    // tail: 64 -> 12 via MFMA (padded to 16), KCH=2 single-barrier, fp32 body out.
    conv_mfma<64, 16, 16, 1, 4, 2, false, false, true, false, 12, false, 2>
        <<<dim3(8, 32, 1), 256, 0, stream>>>(h_bf, wqt, tail_b, nullptr, 0,
                                             body, nullptr, nullptr, 0);
    // pixel shuffle + fused skip conv
    shuffle_skip<<<1536, 256, 0, stream>>>(body, x, skip_w, skip_b, (float*)d_out);
}

// Round 14
// 315.270 us; speedup vs baseline: 1.0674x; 1.0674x over previous
//
#include <hip/hip_runtime.h>

typedef __attribute__((ext_vector_type(8))) short bf16x8;
typedef __attribute__((ext_vector_type(4))) float f32x4;
typedef __attribute__((ext_vector_type(8))) unsigned short u16x8;

__device__ __forceinline__ unsigned short bf16u(float x) {
    unsigned int u = __builtin_bit_cast(unsigned int, x);
    unsigned int r = (u + 0x7fffu + ((u >> 16) & 1u)) >> 16;
    return (unsigned short)r;
}
__device__ __forceinline__ float bf2f(unsigned short u) {
    return __builtin_bit_cast(float, (unsigned int)u << 16);
}
__device__ __forceinline__ void gll16(const void* g, void* l) {
    __builtin_amdgcn_global_load_lds((const __attribute__((address_space(1))) void*)g,
                                     (__attribute__((address_space(3))) void*)l, 16, 0, 0);
}

// ---------------------------------------------------------------------------
// Setup: blocks [0,335) zero h_bf/t_bf borders + sum buffers;
//        blocks [335,411) weight-norm head (64) + skip (12);
//        blocks [411,427) tail weight-norm + fragment repack (16 mo rows).
// ---------------------------------------------------------------------------
__global__ __launch_bounds__(256) void setup_kernel(
    unsigned short* __restrict__ hbf, unsigned short* __restrict__ tbf,
    float* __restrict__ sums,
    const float* __restrict__ hv, const float* __restrict__ hg, float* __restrict__ hw,
    const float* __restrict__ kv, const float* __restrict__ kg, float* __restrict__ kw,
    const float* __restrict__ tv, const float* __restrict__ tg,
    unsigned short* __restrict__ wqt) {
    int blk = blockIdx.x;
    int tid = threadIdx.x;
    if (blk < 335) {
        int i = blk * 256 + tid;
        u16x8 z8 = {0, 0, 0, 0, 0, 0, 0, 0};
        if (i < 16640) {          // h_bf borders: 16 slabs * 260 * 4 chunks
            int chv = i & 3, pb = i >> 2, pos = pb % 260, bc = pb / 260;
            int y, x;
            if (pos < 66) { y = 0; x = pos; }
            else if (pos < 132) { y = 65; x = pos - 66; }
            else if (pos < 196) { y = pos - 131; x = 0; }
            else { y = pos - 195; x = 65; }
            *(u16x8*)&hbf[((size_t)bc * 4356 + y * 66 + x) * 32 + chv * 8] = z8;
        } else if (i < 83200) {   // t_bf borders: 64 slabs * 260 * 4 chunks
            int j = i - 16640;
            int chv = j & 3, pb = j >> 2, pos = pb % 260, bc = pb / 260;
            int y, x;
            if (pos < 66) { y = 0; x = pos; }
            else if (pos < 132) { y = 65; x = pos - 66; }
            else if (pos < 196) { y = pos - 131; x = 0; }
            else { y = pos - 195; x = 65; }
            *(u16x8*)&tbf[((size_t)bc * 4356 + y * 66 + x) * 32 + chv * 8] = z8;
        } else {
            int k = i - 83200;    // < 2560
            f32x4 z4 = {0.f, 0.f, 0.f, 0.f};
            ((f32x4*)sums)[k] = z4;
        }
        return;
    }
    __shared__ float srow[576];
    __shared__ float red[4];
    __shared__ float s_sc;
    if (blk < 411) {
        int b2 = blk - 335;
        const float *v, *g;
        float* outw;
        int len, row;
        if (b2 < 64) { v = hv; g = hg; outw = hw; len = 27; row = b2; }
        else         { v = kv; g = kg; outw = kw; len = 75; row = b2 - 64; }
        const float* vr = v + (size_t)row * len;
        float ss = 0.f;
        for (int i = tid; i < len; i += 256) { float a = vr[i]; ss += a * a; }
        for (int o = 32; o > 0; o >>= 1) ss += __shfl_down(ss, o);
        if ((tid & 63) == 0) red[tid >> 6] = ss;
        __syncthreads();
        if (tid == 0) s_sc = g[row] / sqrtf(red[0] + red[1] + red[2] + red[3]);
        __syncthreads();
        float sc = s_sc;
        float* orow = outw + (size_t)row * len;
        for (int i = tid; i < len; i += 256) orow[i] = vr[i] * sc;
        return;
    }
    int mo = blk - 411;
    if (mo < 12) {
        for (int i = tid; i < 576; i += 256) srow[i] = tv[mo * 576 + i];
        __syncthreads();
        float ss = 0.f;
        for (int i = tid; i < 576; i += 256) { float a = srow[i]; ss += a * a; }
        for (int o = 32; o > 0; o >>= 1) ss += __shfl_down(ss, o);
        if ((tid & 63) == 0) red[tid >> 6] = ss;
        __syncthreads();
        if (tid == 0) s_sc = tg[mo] / sqrtf(red[0] + red[1] + red[2] + red[3]);
        __syncthreads();
        float sc = s_sc;
        for (int ch = tid; ch < 72; ch += 256) {
            int kg = ch & 3, c2 = ch >> 2;
            int t = c2 % 9, kc = c2 / 9;
            u16x8 pk;
#pragma unroll
            for (int kj = 0; kj < 8; ++kj) {
                int ic = kc * 32 + kg * 8 + kj;
                pk[kj] = bf16u(srow[ic * 9 + t] * sc);
            }
            *(u16x8*)&wqt[(size_t)((kc * 9 + t) * 4 + kg) * 128 + mo * 8] = pk;
        }
    } else {
        u16x8 z = {0, 0, 0, 0, 0, 0, 0, 0};
        for (int ch = tid; ch < 72; ch += 256) {
            int kg = ch & 3, c2 = ch >> 2;
            int t = c2 % 9, kc = c2 / 9;
            *(u16x8*)&wqt[(size_t)((kc * 9 + t) * 4 + kg) * 128 + mo * 8] = z;
        }
    }
}

// ---------------------------------------------------------------------------
// combine_v4: wn-fused per-sample weight combine + routing softmax.
// One block = GOC output channels x ONE sample. grid (OC/GOC, 8).
// wq layout [b][ot][kc][t][kg][mo(2^LGMO)][kj(8)].
// ---------------------------------------------------------------------------
template <int IC, int GOC, int LGMO>
__global__ __launch_bounds__(256) void combine_v4(
    const float* __restrict__ v, const float* __restrict__ g,
    const float* __restrict__ msum, const float* __restrict__ mw,
    const float* __restrict__ mb, float* __restrict__ s_out,
    unsigned short* __restrict__ wq, int D, int OC) {
    constexpr int ROWF = IC * 9;
    constexpr int KCh = IC / 32;
    constexpr int ROWS2 = 2 * GOC;
    constexpr int TOTC = GOC * KCh * 9 * 4;
    constexpr int TPR = 256 / ROWS2;
    __shared__ float lv[ROWS2 * ROWF];
    __shared__ float lg[8], sv8[8], scr[ROWS2], sw[ROWS2];
    int tid = threadIdx.x;
    int ocg = blockIdx.x * GOC;
    int b = blockIdx.y;
    for (int i = tid; i < ROWS2 * ROWF; i += 256) {
        int r = i / ROWF, jj = i - r * ROWF;
        int oc_r = (r / GOC) * OC + ocg + (r % GOC);
        lv[i] = v[(size_t)oc_r * ROWF + jj];
    }
    {
        int j = tid >> 5, l32 = tid & 31;
        float part = 0.f;
        for (int i = l32; i < IC; i += 32) part += msum[b * IC + i] * mw[j * IC + i];
        for (int m = 16; m > 0; m >>= 1) part += __shfl_xor(part, m);
        if (l32 == 0) lg[j] = part * (1.f / 4096.f) + mb[j];
    }
    __syncthreads();
    {
        int r = tid / TPR, lr = tid % TPR;
        float ss = 0.f;
        for (int i = lr; i < ROWF; i += TPR) { float a = lv[r * ROWF + i]; ss += a * a; }
#pragma unroll
        for (int m = TPR >> 1; m > 0; m >>= 1) ss += __shfl_xor(ss, m);
        if (lr == 0) {
            int oc_r = (r / GOC) * OC + ocg + (r % GOC);
            scr[r] = g[oc_r] / sqrtf(ss);
        }
    }
    if (tid < 8) {
        int gg = tid >> 2, c = tid & 3;
        float l0 = lg[c], l1 = lg[4 + c];
        float m = fmaxf(l0, l1);
        float e0 = __expf(l0 - m), e1 = __expf(l1 - m);
        float val = ((gg == 0) ? e0 : e1) / (e0 + e1);
        sv8[tid] = val;
        if (blockIdx.x == 0) s_out[b * 8 + tid] = val;
    }
    __syncthreads();
    if (tid < ROWS2) {
        int r = tid;
        int oc = ocg + (r % GOC);
        int cd = oc / D;
        float s = (r < GOC) ? sv8[cd] : sv8[4 + cd];
        sw[r] = s * scr[r];
    }
    __syncthreads();
    for (int ci = tid; ci < TOTC; ci += 256) {
        int ml = ci % GOC;
        int c = ci / GOC;
        int kg = c & 3, c2 = c >> 2;
        int t = c2 % 9, kc = c2 / 9;
        int oc = ocg + ml;
        float s0 = sw[ml], s1 = sw[GOC + ml];
        const float* p0 = &lv[(size_t)ml * ROWF];
        const float* p1 = &lv[(size_t)(GOC + ml) * ROWF];
        u16x8 pk;
#pragma unroll
        for (int kj = 0; kj < 8; ++kj) {
            int ic9 = (kc * 32 + kg * 8 + kj) * 9 + t;
            pk[kj] = bf16u(s0 * p0[ic9] + s1 * p1[ic9]);
        }
        size_t w_off = ((((size_t)(b * (OC >> LGMO) + (oc >> LGMO)) * KCh + kc) * 9 + t) * 4 + kg)
                           * ((1 << LGMO) * 8) + (size_t)(oc & ((1 << LGMO) - 1)) * 8;
        *(u16x8*)&wq[w_off] = pk;
    }
}

// ---------------------------------------------------------------------------
// MFMA implicit-GEMM 3x3 conv. Input [b][IC/32][66][66][32] bf16 slabs.
// S double-buffered; A-frags global->VGPR 2-tap ring; NF-pair shuffle epilogue.
// s_setprio(1) around each tap's MFMA cluster (T5: blocks run unsynchronized
// at 4/CU -> wave role diversity). grid = (b, strip, ot).
// ---------------------------------------------------------------------------
template <int IC, int OC, int MT, int WM, int WN, int NR,
          bool RELU, bool RES, bool WF32, bool WBF, int OCR, bool DYNB, int MINW>
__global__ __launch_bounds__(WM * WN * 64, MINW)
void conv_mfma(
    const unsigned short* __restrict__ in_bf,
    const unsigned short* __restrict__ wq,
    const float* __restrict__ bias_raw, const float* __restrict__ s8, int lgD,
    float* __restrict__ out,
    unsigned short* __restrict__ out_bf, float* __restrict__ msum, long wstride) {
    constexpr int THREADS = WM * WN * 64;
    constexpr int KCH = IC / 32;
    constexpr int NRH = NR + 2;
    constexpr int NT = NR * 64;
    constexpr int NF = (NT / 16) / WN;
    constexpr int MW = MT / (16 * WM);
    constexpr int WELEM = 9 * 32 * MT;
    constexpr int SELEM = NRH * 66 * 32;
    constexpr int SCH = SELEM / 8;
    constexpr int OCB = OCR / 32;

    __shared__ __align__(16) unsigned short S[2][SELEM];
    __shared__ float MRED[WN][MT];

    const int b = blockIdx.x, ot = blockIdx.z;
    const int y0 = blockIdx.y * NR;
    const int tid = threadIdx.x;
    const int lane = tid & 63;
    const int wid = tid >> 6;
    const int wm = wid / WN, wn = wid % WN;
    const int l15 = lane & 15, lk = lane >> 4;
    const int wmo = wm * (MT / WM);
    const int wno = wn * (NT / WN);

    f32x4 acc[MW][NF];
#pragma unroll
    for (int mf = 0; mf < MW; ++mf)
#pragma unroll
        for (int nf = 0; nf < NF; ++nf)
#pragma unroll
            for (int q = 0; q < 4; ++q) acc[mf][nf][q] = 0.f;

    const unsigned short* inb = in_bf + (size_t)b * KCH * (4356 * 32);
    const unsigned short* wqb = wq + (size_t)b * wstride + (size_t)ot * (KCH * WELEM);
    const unsigned short* wqa = wqb + (size_t)lk * (MT * 8) + (size_t)(wmo + l15) * 8;

    auto STAGE_S = [&](int kc, int buf) {
        const unsigned short* sb = inb + (size_t)kc * (4356 * 32);
        for (int i = tid; i < SCH; i += THREADS) {
            int Lz = i ^ ((i >> 3) & 7);
            int lk2 = Lz & 3, cr = Lz >> 2;
            int col = cr % 66, row = cr / 66;
            gll16(sb + ((size_t)(y0 + row) * 66 + col) * 32 + lk2 * 8,
                  (char*)S[buf] + i * 16);
        }
    };

    bf16x8 aT[2][MW];
#pragma unroll
    for (int mf = 0; mf < MW; ++mf) {
        aT[0][mf] = *(const bf16x8*)(wqa + mf * (16 * 8));
        aT[1][mf] = *(const bf16x8*)(wqa + (4 * MT * 8) + mf * (16 * 8));
    }
    STAGE_S(0, 0);
    __syncthreads();
#pragma unroll
    for (int kc = 0; kc < KCH; ++kc) {
        if (kc + 1 < KCH) STAGE_S(kc + 1, (kc + 1) & 1);
        const unsigned short* Sb = S[kc & 1];
#pragma unroll
        for (int t = 0; t < 9; ++t) {
            const int gt = kc * 9 + t;
            const int pp = gt & 1;
            const int dy = t / 3, dx = t % 3;
            __builtin_amdgcn_s_setprio(1);
#pragma unroll
            for (int nf = 0; nf < NF; ++nf) {
                int n = wno + nf * 16 + l15;
                int r = n >> 6, c = n & 63;
                int L = ((r + dy) * 66 + (c + dx)) * 4 + lk;
                int P = L ^ ((L >> 3) & 7);
                bf16x8 bv = *(const bf16x8*)((const char*)Sb + P * 16);
#pragma unroll
                for (int mf = 0; mf < MW; ++mf)
                    acc[mf][nf] = __builtin_amdgcn_mfma_f32_16x16x32_bf16(aT[pp][mf], bv, acc[mf][nf], 0, 0, 0);
            }
            __builtin_amdgcn_s_setprio(0);
            if (gt + 2 < KCH * 9) {
                const int ngt = gt + 2;
                const int nkc = ngt / 9, nt2 = ngt % 9;
#pragma unroll
                for (int mf = 0; mf < MW; ++mf)
                    aT[pp][mf] = *(const bf16x8*)(wqa + (size_t)nkc * WELEM + nt2 * (4 * MT * 8) + mf * (16 * 8));
            }
        }
        __syncthreads();
    }

    if constexpr (WBF) {
        const int ch = lk >> 1;
        const bool oddlk = (lk & 1);
#pragma unroll
        for (int mf = 0; mf < MW; ++mf) {
            int ocb = ot * MT + wmo + mf * 16 + lk * 4;
            float bvv[4];
#pragma unroll
            for (int q = 0; q < 4; ++q) {
                int oc = ocb + q;
                if (DYNB) {
                    int cc = oc >> lgD;
                    bvv[q] = s8[b * 8 + cc] * bias_raw[oc] + s8[b * 8 + 4 + cc] * bias_raw[OCR + oc];
                } else {
                    bvv[q] = bias_raw[oc];
                }
            }
            int occ = ot * MT + wmo + mf * 16 + ch * 8;
            float msr8[8];
#pragma unroll
            for (int j = 0; j < 8; ++j) msr8[j] = 0.f;
#pragma unroll
            for (int nfp = 0; nfp < NF; nfp += 2) {
                float r0[2][4], pr[2][4];
#pragma unroll
                for (int h = 0; h < 2; ++h)
#pragma unroll
                    for (int q = 0; q < 4; ++q) {
                        float v = acc[mf][nfp + h][q] + bvv[q];
                        if (RELU) v = fmaxf(v, 0.f);
                        r0[h][q] = v;
                    }
#pragma unroll
                for (int h = 0; h < 2; ++h)
#pragma unroll
                    for (int q = 0; q < 4; ++q) pr[h][q] = __shfl_xor(r0[h][q], 16);
                float v8[8];
#pragma unroll
                for (int q = 0; q < 4; ++q) {
                    float own = oddlk ? r0[1][q] : r0[0][q];
                    float oth = oddlk ? pr[1][q] : pr[0][q];
                    v8[q]     = oddlk ? oth : own;
                    v8[4 + q] = oddlk ? own : oth;
                }
                int mynf = nfp + (lk & 1);
                int n = wno + mynf * 16 + l15;
                int y = y0 + (n >> 6), x = n & 63;
                size_t addr = ((((size_t)b * OCB + (occ >> 5)) * 66 + (y + 1)) * 66 + (x + 1)) * 32
                              + (occ & 31);
                if (RES) {
                    u16x8 rv = *(const u16x8*)&out_bf[addr];
#pragma unroll
                    for (int j = 0; j < 8; ++j) v8[j] += bf2f(rv[j]);
                }
                u16x8 pk;
#pragma unroll
                for (int j = 0; j < 8; ++j) pk[j] = bf16u(v8[j]);
                *(u16x8*)&out_bf[addr] = pk;
#pragma unroll
                for (int j = 0; j < 8; ++j) msr8[j] += v8[j];
            }
            if (msum) {
#pragma unroll
                for (int j = 0; j < 8; ++j) {
                    float t = msr8[j];
                    t += __shfl_xor(t, 1);
                    t += __shfl_xor(t, 2);
                    t += __shfl_xor(t, 4);
                    t += __shfl_xor(t, 8);
                    t += __shfl_xor(t, 16);
                    msr8[j] = t;
                }
                if ((lane & 31) == 0) {
#pragma unroll
                    for (int j = 0; j < 8; ++j)
                        MRED[wn][wmo + mf * 16 + ch * 8 + j] = msr8[j];
                }
            }
        }
        if (msum) {
            __syncthreads();
            if (tid < MT) {
                float tot = 0.f;
#pragma unroll
                for (int w2 = 0; w2 < WN; ++w2) tot += MRED[w2][tid];
                atomicAdd(&msum[b * OCR + ot * MT + tid], tot);
            }
        }
    }
    if constexpr (WF32) {
#pragma unroll
        for (int mf = 0; mf < MW; ++mf) {
            int ocb = ot * MT + wmo + mf * 16 + lk * 4;
#pragma unroll
            for (int nf = 0; nf < NF; ++nf) {
                int n = wno + nf * 16 + l15;
                int y = y0 + (n >> 6), x = n & 63;
#pragma unroll
                for (int q = 0; q < 4; ++q) {
                    int oc = ocb + q;
                    if (oc < OCR) {
                        float v = acc[mf][nf][q] + bias_raw[oc];
                        out[(((size_t)b * OCR + oc) * 64 + y) * 64 + x] = v;
                    }
                }
            }
        }
    }
}

// ---------------------------------------------------------------------------
// Head conv 3->64 direct fp32; OCT=8, 256 blocks (1/CU). Writes h_bf + hsum0.
// ---------------------------------------------------------------------------
__global__ __launch_bounds__(256) void head_conv(
    const float* __restrict__ in, const float* __restrict__ w,
    const float* __restrict__ bias,
    unsigned short* __restrict__ out_bf, float* __restrict__ hsum0) {
    constexpr int OCT = 8, IC = 3;
    __shared__ float s_in[34 * 34];
    __shared__ float s_w[OCT * 9];
    __shared__ float wred[4][OCT];
    int b = blockIdx.z;
    int ocBase = blockIdx.y * OCT;
    int ty0 = (blockIdx.x >> 1) * 32;
    int tx0 = (blockIdx.x & 1) * 32;
    int tid = threadIdx.x;
    int lane = tid & 63, wid = tid >> 6;
    int tx = tid & 15, ty = tid >> 4;

    float acc[OCT][4];
#pragma unroll
    for (int oc = 0; oc < OCT; ++oc)
#pragma unroll
        for (int p = 0; p < 4; ++p) acc[oc][p] = 0.f;

    const float* inb = in + (size_t)b * IC * 4096;
    for (int ic = 0; ic < IC; ++ic) {
        const float* src = inb + (size_t)ic * 4096;
        for (int i = tid; i < 34 * 34; i += 256) {
            int r = i / 34, cc = i % 34;
            int gy = ty0 + r - 1, gx = tx0 + cc - 1;
            float val = 0.f;
            if (gy >= 0 && gy < 64 && gx >= 0 && gx < 64) val = src[gy * 64 + gx] - 0.5f;
            s_in[i] = val;
        }
        for (int i = tid; i < OCT * 9; i += 256) {
            int oc = i / 9, t = i % 9;
            s_w[i] = w[((size_t)(ocBase + oc) * IC + ic) * 9 + t];
        }
        __syncthreads();
        float v[4][4];
#pragma unroll
        for (int r = 0; r < 4; ++r)
#pragma unroll
            for (int cc = 0; cc < 4; ++cc) v[r][cc] = s_in[(2 * ty + r) * 34 + (2 * tx + cc)];
#pragma unroll
        for (int oc = 0; oc < OCT; ++oc) {
#pragma unroll
            for (int ky = 0; ky < 3; ++ky)
#pragma unroll
                for (int kx = 0; kx < 3; ++kx) {
                    float wv = s_w[oc * 9 + ky * 3 + kx];
                    acc[oc][0] += wv * v[ky][kx];
                    acc[oc][1] += wv * v[ky][kx + 1];
                    acc[oc][2] += wv * v[ky + 1][kx];
                    acc[oc][3] += wv * v[ky + 1][kx + 1];
                }
        }
        __syncthreads();
    }
    int py = ty0 + 2 * ty, px = tx0 + 2 * tx;
#pragma unroll
    for (int oc = 0; oc < OCT; ++oc) {
        int og = ocBase + oc;
        float bv = bias[og];
        float osum = 0.f;
#pragma unroll
        for (int p = 0; p < 4; ++p) {
            int dy = p >> 1, dx = p & 1;
            float val = acc[oc][p] + bv;
            osum += val;
            out_bf[((size_t)(b * 2 + (og >> 5)) * 4356 + (py + dy + 1) * 66 + (px + dx + 1)) * 32
                   + (og & 31)] = bf16u(val);
        }
        for (int m = 1; m < 64; m <<= 1) osum += __shfl_xor(osum, m);
        if (lane == 0) wred[wid][oc] = osum;
    }
    __syncthreads();
    if (tid < OCT)
        atomicAdd(&hsum0[b * 64 + ocBase + tid],
                  wred[0][tid] + wred[1][tid] + wred[2][tid] + wred[3][tid]);
}

// ---------------------------------------------------------------------------
// Pixel shuffle + fused 5x5 skip conv + IMAGE_MEAN. out [8,3,128,128]
// ---------------------------------------------------------------------------
__global__ __launch_bounds__(256) void shuffle_skip(
    const float* __restrict__ body, const float* __restrict__ x,
    const float* __restrict__ skw, const float* __restrict__ skb,
    float* __restrict__ out) {
    __shared__ float w[900];
    __shared__ float bb[12];
    int tid = threadIdx.x;
    for (int i = tid; i < 900; i += 256) w[i] = skw[i];
    if (tid < 12) bb[tid] = skb[tid];
    __syncthreads();
    int idx = blockIdx.x * 256 + tid;
    int ox = idx & 127;
    int oy = (idx >> 7) & 127;
    int v = idx >> 14;
    int c = v % 3;
    int b = v / 3;
    int rx = ox & 1, ry = oy & 1;
    int xx = ox >> 1, yy = oy >> 1;
    int ch = c * 4 + ry * 2 + rx;
    float acc = bb[ch];
    for (int ic = 0; ic < 3; ++ic)
        for (int ky = 0; ky < 5; ++ky) {
            int gy = yy + ky - 2;
            if (gy < 0 || gy >= 64) continue;
            for (int kx = 0; kx < 5; ++kx) {
                int gx = xx + kx - 2;
                if (gx < 0 || gx >= 64) continue;
                acc += w[((ch * 3 + ic) * 5 + ky) * 5 + kx] *
                       (x[((size_t)(b * 3 + ic) * 64 + gy) * 64 + gx] - 0.5f);
            }
        }
    size_t src = (((size_t)b * 12 + ch) * 64 + yy) * 64 + xx;
    out[idx] = body[src] + acc + 0.5f;
}

// ---------------------------------------------------------------------------
extern "C" void kernel_launch(void* const* d_in, const int* in_sizes, int n_in,
                              void* d_out, int out_size, void* d_ws, size_t ws_size,
                              hipStream_t stream) {
    const float* x      = (const float*)d_in[0];
    const float* head_v = (const float*)d_in[1];
    const float* head_g = (const float*)d_in[2];
    const float* head_b = (const float*)d_in[3];
    const float* b1_v   = (const float*)d_in[4];
    const float* b1_g   = (const float*)d_in[5];
    const float* b1_b   = (const float*)d_in[6];
    const float* b1_mw  = (const float*)d_in[7];
    const float* b1_mb  = (const float*)d_in[8];
    const float* b2_v   = (const float*)d_in[9];
    const float* b2_g   = (const float*)d_in[10];
    const float* b2_b   = (const float*)d_in[11];
    const float* b2_mw  = (const float*)d_in[12];
    const float* b2_mb  = (const float*)d_in[13];
    const float* tail_v = (const float*)d_in[14];
    const float* tail_g = (const float*)d_in[15];
    const float* tail_b = (const float*)d_in[16];
    const float* skip_v = (const float*)d_in[17];
    const float* skip_g = (const float*)d_in[18];
    const float* skip_b = (const float*)d_in[19];

    float* ws = (float*)d_ws;
    size_t off = 0;
    auto alloc = [&](size_t n) { float* p = ws + off; off += (n + 3) & ~(size_t)3; return p; };
    float* head_w = alloc(64 * 27);
    float* skip_w = alloc(12 * 75);
    float* sums   = alloc(10240);   // hsum[4] @ l*512 ; tsum[4] @ 2048 + l*2048
    float* sbuf   = alloc(64);
    float* body   = alloc((size_t)8 * 12 * 4096);
    unsigned short* wq1  = (unsigned short*)alloc((size_t)8 * 256 * 576 / 2);
    unsigned short* wq2  = (unsigned short*)alloc((size_t)8 * 64 * 2304 / 2);
    unsigned short* wqt  = (unsigned short*)alloc(9216 / 2);
    unsigned short* h_bf = (unsigned short*)alloc((size_t)8 * 2 * 4356 * 32 / 2);
    unsigned short* t_bf = (unsigned short*)alloc((size_t)8 * 8 * 4356 * 32 / 2);
    (void)ws_size; (void)in_sizes; (void)n_in; (void)out_size;

    auto hsum = [&](int l) { return sums + l * 512; };
    auto tsum = [&](int l) { return sums + 2048 + l * 2048; };

    setup_kernel<<<427, 256, 0, stream>>>(h_bf, t_bf, sums, head_v, head_g, head_w,
                                          skip_v, skip_g, skip_w, tail_v, tail_g, wqt);
    head_conv<<<dim3(4, 8, 8), 256, 0, stream>>>(x, head_w, head_b, h_bf, hsum(0));

    for (int l = 0; l < 4; ++l) {
        // dyn conv 1: 64 -> 256, relu. WM=2/WN=2/NR=2, 1024 blocks, 4/CU.
        combine_v4<64, 4, 6><<<dim3(64, 8), 256, 0, stream>>>(
            b1_v + (size_t)l * 512 * 576, b1_g + (size_t)l * 512, hsum(l),
            b1_mw + (size_t)l * 8 * 64, b1_mb + l * 8, sbuf, wq1, 64, 256);
        conv_mfma<64, 256, 64, 2, 2, 2, true, false, false, true, 256, true, 4>
            <<<dim3(8, 32, 4), 256, 0, stream>>>(h_bf, wq1, b1_b + (size_t)l * 512, sbuf, 6,
                                                 nullptr, t_bf, tsum(l), 147456);
        // dyn conv 2: 256 -> 64, bf16 in-place residual. WM=4/WN=2/NR=1, 512thr.
        combine_v4<256, 2, 6><<<dim3(32, 8), 256, 0, stream>>>(
            b2_v + (size_t)l * 128 * 2304, b2_g + (size_t)l * 128, tsum(l),
            b2_mw + (size_t)l * 8 * 256, b2_mb + l * 8, sbuf, wq2, 16, 64);
        conv_mfma<256, 64, 64, 4, 2, 1, false, true, false, true, 64, true, 4>
            <<<dim3(8, 64, 1), 512, 0, stream>>>(t_bf, wq2, b2_b + (size_t)l * 128, sbuf, 4,
                                                 nullptr, h_bf, (l < 3) ? hsum(l + 1) : nullptr,
                                                 147456);
    }

    // tail: 64 -> 12 via MFMA (padded to 16), fp32 body out. NR=2, 256 blocks.
    conv_mfma<64, 16, 16, 1, 4, 2, false, false, true, false, 12, false, 2>
        <<<dim3(8, 32, 1), 256, 0, stream>>>(h_bf, wqt, tail_b, nullptr, 0,
                                             body, nullptr, nullptr, 0);
    // pixel shuffle + fused skip conv
    shuffle_skip<<<1536, 256, 0, stream>>>(body, x, skip_w, skip_b, (float*)d_out);
}

// Round 15
// 303.183 us; speedup vs baseline: 1.1100x; 1.0399x over previous
//
#include <hip/hip_runtime.h>

typedef __attribute__((ext_vector_type(8))) short bf16x8;
typedef __attribute__((ext_vector_type(4))) float f32x4;
typedef __attribute__((ext_vector_type(8))) unsigned short u16x8;

__device__ __forceinline__ unsigned short bf16u(float x) {
    unsigned int u = __builtin_bit_cast(unsigned int, x);
    unsigned int r = (u + 0x7fffu + ((u >> 16) & 1u)) >> 16;
    return (unsigned short)r;
}
__device__ __forceinline__ float bf2f(unsigned short u) {
    return __builtin_bit_cast(float, (unsigned int)u << 16);
}
__device__ __forceinline__ void gll16(const void* g, void* l) {
    __builtin_amdgcn_global_load_lds((const __attribute__((address_space(1))) void*)g,
                                     (__attribute__((address_space(3))) void*)l, 16, 0, 0);
}

// ---------------------------------------------------------------------------
// Setup: blocks [0,335) zero h_bf/t_bf borders + sum buffers;
//        blocks [335,351) tail weight-norm + fragment repack (16 mo rows).
// ---------------------------------------------------------------------------
__global__ __launch_bounds__(256) void setup_kernel(
    unsigned short* __restrict__ hbf, unsigned short* __restrict__ tbf,
    float* __restrict__ sums,
    const float* __restrict__ tv, const float* __restrict__ tg,
    unsigned short* __restrict__ wqt) {
    int blk = blockIdx.x;
    int tid = threadIdx.x;
    if (blk < 335) {
        int i = blk * 256 + tid;
        u16x8 z8 = {0, 0, 0, 0, 0, 0, 0, 0};
        if (i < 16640) {          // h_bf borders: 16 slabs * 260 * 4 chunks
            int chv = i & 3, pb = i >> 2, pos = pb % 260, bc = pb / 260;
            int y, x;
            if (pos < 66) { y = 0; x = pos; }
            else if (pos < 132) { y = 65; x = pos - 66; }
            else if (pos < 196) { y = pos - 131; x = 0; }
            else { y = pos - 195; x = 65; }
            *(u16x8*)&hbf[((size_t)bc * 4356 + y * 66 + x) * 32 + chv * 8] = z8;
        } else if (i < 83200) {   // t_bf borders: 64 slabs * 260 * 4 chunks
            int j = i - 16640;
            int chv = j & 3, pb = j >> 2, pos = pb % 260, bc = pb / 260;
            int y, x;
            if (pos < 66) { y = 0; x = pos; }
            else if (pos < 132) { y = 65; x = pos - 66; }
            else if (pos < 196) { y = pos - 131; x = 0; }
            else { y = pos - 195; x = 65; }
            *(u16x8*)&tbf[((size_t)bc * 4356 + y * 66 + x) * 32 + chv * 8] = z8;
        } else {
            int k = i - 83200;    // < 2560
            f32x4 z4 = {0.f, 0.f, 0.f, 0.f};
            ((f32x4*)sums)[k] = z4;
        }
        return;
    }
    // tail repack: one block per mo
    __shared__ float srow[576];
    __shared__ float red[4];
    __shared__ float s_sc;
    int mo = blk - 335;
    if (mo < 12) {
        for (int i = tid; i < 576; i += 256) srow[i] = tv[mo * 576 + i];
        __syncthreads();
        float ss = 0.f;
        for (int i = tid; i < 576; i += 256) { float a = srow[i]; ss += a * a; }
        for (int o = 32; o > 0; o >>= 1) ss += __shfl_down(ss, o);
        if ((tid & 63) == 0) red[tid >> 6] = ss;
        __syncthreads();
        if (tid == 0) s_sc = tg[mo] / sqrtf(red[0] + red[1] + red[2] + red[3]);
        __syncthreads();
        float sc = s_sc;
        for (int ch = tid; ch < 72; ch += 256) {
            int kg = ch & 3, c2 = ch >> 2;
            int t = c2 % 9, kc = c2 / 9;
            u16x8 pk;
#pragma unroll
            for (int kj = 0; kj < 8; ++kj) {
                int ic = kc * 32 + kg * 8 + kj;
                pk[kj] = bf16u(srow[ic * 9 + t] * sc);
            }
            *(u16x8*)&wqt[(size_t)((kc * 9 + t) * 4 + kg) * 128 + mo * 8] = pk;
        }
    } else {
        u16x8 z = {0, 0, 0, 0, 0, 0, 0, 0};
        for (int ch = tid; ch < 72; ch += 256) {
            int kg = ch & 3, c2 = ch >> 2;
            int t = c2 % 9, kc = c2 / 9;
            *(u16x8*)&wqt[(size_t)((kc * 9 + t) * 4 + kg) * 128 + mo * 8] = z;
        }
    }
}

// ---------------------------------------------------------------------------
// combine_v4: wn-fused per-sample weight combine + routing softmax.
// One block = GOC output channels x ONE sample. grid (OC/GOC, 8).
// wq layout [b][ot][kc][t][kg][mo(2^LGMO)][kj(8)].
// ---------------------------------------------------------------------------
template <int IC, int GOC, int LGMO>
__global__ __launch_bounds__(256) void combine_v4(
    const float* __restrict__ v, const float* __restrict__ g,
    const float* __restrict__ msum, const float* __restrict__ mw,
    const float* __restrict__ mb, float* __restrict__ s_out,
    unsigned short* __restrict__ wq, int D, int OC) {
    constexpr int ROWF = IC * 9;
    constexpr int KCh = IC / 32;
    constexpr int ROWS2 = 2 * GOC;
    constexpr int TOTC = GOC * KCh * 9 * 4;
    constexpr int TPR = 256 / ROWS2;
    __shared__ float lv[ROWS2 * ROWF];
    __shared__ float lg[8], sv8[8], scr[ROWS2], sw[ROWS2];
    int tid = threadIdx.x;
    int ocg = blockIdx.x * GOC;
    int b = blockIdx.y;
    for (int i = tid; i < ROWS2 * ROWF; i += 256) {
        int r = i / ROWF, jj = i - r * ROWF;
        int oc_r = (r / GOC) * OC + ocg + (r % GOC);
        lv[i] = v[(size_t)oc_r * ROWF + jj];
    }
    {
        int j = tid >> 5, l32 = tid & 31;
        float part = 0.f;
        for (int i = l32; i < IC; i += 32) part += msum[b * IC + i] * mw[j * IC + i];
        for (int m = 16; m > 0; m >>= 1) part += __shfl_xor(part, m);
        if (l32 == 0) lg[j] = part * (1.f / 4096.f) + mb[j];
    }
    __syncthreads();
    {
        int r = tid / TPR, lr = tid % TPR;
        float ss = 0.f;
        for (int i = lr; i < ROWF; i += TPR) { float a = lv[r * ROWF + i]; ss += a * a; }
#pragma unroll
        for (int m = TPR >> 1; m > 0; m >>= 1) ss += __shfl_xor(ss, m);
        if (lr == 0) {
            int oc_r = (r / GOC) * OC + ocg + (r % GOC);
            scr[r] = g[oc_r] / sqrtf(ss);
        }
    }
    if (tid < 8) {
        int gg = tid >> 2, c = tid & 3;
        float l0 = lg[c], l1 = lg[4 + c];
        float m = fmaxf(l0, l1);
        float e0 = __expf(l0 - m), e1 = __expf(l1 - m);
        float val = ((gg == 0) ? e0 : e1) / (e0 + e1);
        sv8[tid] = val;
        if (blockIdx.x == 0) s_out[b * 8 + tid] = val;
    }
    __syncthreads();
    if (tid < ROWS2) {
        int r = tid;
        int oc = ocg + (r % GOC);
        int cd = oc / D;
        float s = (r < GOC) ? sv8[cd] : sv8[4 + cd];
        sw[r] = s * scr[r];
    }
    __syncthreads();
    for (int ci = tid; ci < TOTC; ci += 256) {
        int ml = ci % GOC;
        int c = ci / GOC;
        int kg = c & 3, c2 = c >> 2;
        int t = c2 % 9, kc = c2 / 9;
        int oc = ocg + ml;
        float s0 = sw[ml], s1 = sw[GOC + ml];
        const float* p0 = &lv[(size_t)ml * ROWF];
        const float* p1 = &lv[(size_t)(GOC + ml) * ROWF];
        u16x8 pk;
#pragma unroll
        for (int kj = 0; kj < 8; ++kj) {
            int ic9 = (kc * 32 + kg * 8 + kj) * 9 + t;
            pk[kj] = bf16u(s0 * p0[ic9] + s1 * p1[ic9]);
        }
        size_t w_off = ((((size_t)(b * (OC >> LGMO) + (oc >> LGMO)) * KCh + kc) * 9 + t) * 4 + kg)
                           * ((1 << LGMO) * 8) + (size_t)(oc & ((1 << LGMO) - 1)) * 8;
        *(u16x8*)&wq[w_off] = pk;
    }
}

// ---------------------------------------------------------------------------
// MFMA implicit-GEMM 3x3 conv. Input [b][IC/32][66][66][32] bf16 slabs.
// S double-buffered; A-frags global->VGPR 2-tap ring; NF-pair shuffle epilogue
// with dense u16x8 stores, in-place bf16 residual, fused msum.
// WF32: fp32 NCHW output (tail). grid = (b, strip, ot).
// ---------------------------------------------------------------------------
template <int IC, int OC, int MT, int WM, int WN, int NR,
          bool RELU, bool RES, bool WF32, bool WBF, int OCR, bool DYNB, int MINW>
__global__ __launch_bounds__(WM * WN * 64, MINW)
void conv_mfma(
    const unsigned short* __restrict__ in_bf,
    const unsigned short* __restrict__ wq,
    const float* __restrict__ bias_raw, const float* __restrict__ s8, int lgD,
    float* __restrict__ out,
    unsigned short* __restrict__ out_bf, float* __restrict__ msum, long wstride) {
    constexpr int THREADS = WM * WN * 64;
    constexpr int KCH = IC / 32;
    constexpr int NRH = NR + 2;
    constexpr int NT = NR * 64;
    constexpr int NF = (NT / 16) / WN;
    constexpr int MW = MT / (16 * WM);
    constexpr int WELEM = 9 * 32 * MT;
    constexpr int SELEM = NRH * 66 * 32;
    constexpr int SCH = SELEM / 8;
    constexpr int OCB = OCR / 32;

    __shared__ __align__(16) unsigned short S[2][SELEM];
    __shared__ float MRED[WN][MT];

    const int b = blockIdx.x, ot = blockIdx.z;
    const int y0 = blockIdx.y * NR;
    const int tid = threadIdx.x;
    const int lane = tid & 63;
    const int wid = tid >> 6;
    const int wm = wid / WN, wn = wid % WN;
    const int l15 = lane & 15, lk = lane >> 4;
    const int wmo = wm * (MT / WM);
    const int wno = wn * (NT / WN);

    f32x4 acc[MW][NF];
#pragma unroll
    for (int mf = 0; mf < MW; ++mf)
#pragma unroll
        for (int nf = 0; nf < NF; ++nf)
#pragma unroll
            for (int q = 0; q < 4; ++q) acc[mf][nf][q] = 0.f;

    const unsigned short* inb = in_bf + (size_t)b * KCH * (4356 * 32);
    const unsigned short* wqb = wq + (size_t)b * wstride + (size_t)ot * (KCH * WELEM);
    const unsigned short* wqa = wqb + (size_t)lk * (MT * 8) + (size_t)(wmo + l15) * 8;

    auto STAGE_S = [&](int kc, int buf) {
        const unsigned short* sb = inb + (size_t)kc * (4356 * 32);
        for (int i = tid; i < SCH; i += THREADS) {
            int Lz = i ^ ((i >> 3) & 7);
            int lk2 = Lz & 3, cr = Lz >> 2;
            int col = cr % 66, row = cr / 66;
            gll16(sb + ((size_t)(y0 + row) * 66 + col) * 32 + lk2 * 8,
                  (char*)S[buf] + i * 16);
        }
    };

    bf16x8 aT[2][MW];
#pragma unroll
    for (int mf = 0; mf < MW; ++mf) {
        aT[0][mf] = *(const bf16x8*)(wqa + mf * (16 * 8));
        aT[1][mf] = *(const bf16x8*)(wqa + (4 * MT * 8) + mf * (16 * 8));
    }
    STAGE_S(0, 0);
    __syncthreads();
#pragma unroll
    for (int kc = 0; kc < KCH; ++kc) {
        if (kc + 1 < KCH) STAGE_S(kc + 1, (kc + 1) & 1);
        const unsigned short* Sb = S[kc & 1];
#pragma unroll
        for (int t = 0; t < 9; ++t) {
            const int gt = kc * 9 + t;
            const int pp = gt & 1;
            const int dy = t / 3, dx = t % 3;
#pragma unroll
            for (int nf = 0; nf < NF; ++nf) {
                int n = wno + nf * 16 + l15;
                int r = n >> 6, c = n & 63;
                int L = ((r + dy) * 66 + (c + dx)) * 4 + lk;
                int P = L ^ ((L >> 3) & 7);
                bf16x8 bv = *(const bf16x8*)((const char*)Sb + P * 16);
#pragma unroll
                for (int mf = 0; mf < MW; ++mf)
                    acc[mf][nf] = __builtin_amdgcn_mfma_f32_16x16x32_bf16(aT[pp][mf], bv, acc[mf][nf], 0, 0, 0);
            }
            if (gt + 2 < KCH * 9) {
                const int ngt = gt + 2;
                const int nkc = ngt / 9, nt2 = ngt % 9;
#pragma unroll
                for (int mf = 0; mf < MW; ++mf)
                    aT[pp][mf] = *(const bf16x8*)(wqa + (size_t)nkc * WELEM + nt2 * (4 * MT * 8) + mf * (16 * 8));
            }
        }
        __syncthreads();
    }

    if constexpr (WBF) {
        const int ch = lk >> 1;
        const bool oddlk = (lk & 1);
#pragma unroll
        for (int mf = 0; mf < MW; ++mf) {
            int ocb = ot * MT + wmo + mf * 16 + lk * 4;
            float bvv[4];
#pragma unroll
            for (int q = 0; q < 4; ++q) {
                int oc = ocb + q;
                if (DYNB) {
                    int cc = oc >> lgD;
                    bvv[q] = s8[b * 8 + cc] * bias_raw[oc] + s8[b * 8 + 4 + cc] * bias_raw[OCR + oc];
                } else {
                    bvv[q] = bias_raw[oc];
                }
            }
            int occ = ot * MT + wmo + mf * 16 + ch * 8;
            float msr8[8];
#pragma unroll
            for (int j = 0; j < 8; ++j) msr8[j] = 0.f;
#pragma unroll
            for (int nfp = 0; nfp < NF; nfp += 2) {
                float r0[2][4], pr[2][4];
#pragma unroll
                for (int h = 0; h < 2; ++h)
#pragma unroll
                    for (int q = 0; q < 4; ++q) {
                        float v = acc[mf][nfp + h][q] + bvv[q];
                        if (RELU) v = fmaxf(v, 0.f);
                        r0[h][q] = v;
                    }
#pragma unroll
                for (int h = 0; h < 2; ++h)
#pragma unroll
                    for (int q = 0; q < 4; ++q) pr[h][q] = __shfl_xor(r0[h][q], 16);
                float v8[8];
#pragma unroll
                for (int q = 0; q < 4; ++q) {
                    float own = oddlk ? r0[1][q] : r0[0][q];
                    float oth = oddlk ? pr[1][q] : pr[0][q];
                    v8[q]     = oddlk ? oth : own;
                    v8[4 + q] = oddlk ? own : oth;
                }
                int mynf = nfp + (lk & 1);
                int n = wno + mynf * 16 + l15;
                int y = y0 + (n >> 6), x = n & 63;
                size_t addr = ((((size_t)b * OCB + (occ >> 5)) * 66 + (y + 1)) * 66 + (x + 1)) * 32
                              + (occ & 31);
                if (RES) {
                    u16x8 rv = *(const u16x8*)&out_bf[addr];
#pragma unroll
                    for (int j = 0; j < 8; ++j) v8[j] += bf2f(rv[j]);
                }
                u16x8 pk;
#pragma unroll
                for (int j = 0; j < 8; ++j) pk[j] = bf16u(v8[j]);
                *(u16x8*)&out_bf[addr] = pk;
#pragma unroll
                for (int j = 0; j < 8; ++j) msr8[j] += v8[j];
            }
            if (msum) {
#pragma unroll
                for (int j = 0; j < 8; ++j) {
                    float t = msr8[j];
                    t += __shfl_xor(t, 1);
                    t += __shfl_xor(t, 2);
                    t += __shfl_xor(t, 4);
                    t += __shfl_xor(t, 8);
                    t += __shfl_xor(t, 16);
                    msr8[j] = t;
                }
                if ((lane & 31) == 0) {
#pragma unroll
                    for (int j = 0; j < 8; ++j)
                        MRED[wn][wmo + mf * 16 + ch * 8 + j] = msr8[j];
                }
            }
        }
        if (msum) {
            __syncthreads();
            if (tid < MT) {
                float tot = 0.f;
#pragma unroll
                for (int w2 = 0; w2 < WN; ++w2) tot += MRED[w2][tid];
                atomicAdd(&msum[b * OCR + ot * MT + tid], tot);
            }
        }
    }
    if constexpr (WF32) {
#pragma unroll
        for (int mf = 0; mf < MW; ++mf) {
            int ocb = ot * MT + wmo + mf * 16 + lk * 4;
#pragma unroll
            for (int nf = 0; nf < NF; ++nf) {
                int n = wno + nf * 16 + l15;
                int y = y0 + (n >> 6), x = n & 63;
#pragma unroll
                for (int q = 0; q < 4; ++q) {
                    int oc = ocb + q;
                    if (oc < OCR) {
                        float v = acc[mf][nf][q] + bias_raw[oc];
                        out[(((size_t)b * OCR + oc) * 64 + y) * 64 + x] = v;
                    }
                }
            }
        }
    }
}

// ---------------------------------------------------------------------------
// Head conv 3->64 direct fp32, weight-norm fused inline (8 rows x 27 elems).
// OCT=8, grid (4,8,8) = 256 blocks. Writes h_bf (slab-32) + hsum0.
// ---------------------------------------------------------------------------
__global__ __launch_bounds__(256) void head_conv(
    const float* __restrict__ in, const float* __restrict__ hv,
    const float* __restrict__ hg, const float* __restrict__ bias,
    unsigned short* __restrict__ out_bf, float* __restrict__ hsum0) {
    constexpr int OCT = 8, IC = 3;
    __shared__ float s_in[34 * 34];
    __shared__ float s_w[OCT * 9];
    __shared__ float s_scl[OCT];
    __shared__ float wred[4][OCT];
    int b = blockIdx.z;
    int ocBase = blockIdx.y * OCT;
    int ty0 = (blockIdx.x >> 1) * 32;
    int tx0 = (blockIdx.x & 1) * 32;
    int tid = threadIdx.x;
    int lane = tid & 63, wid = tid >> 6;
    int tx = tid & 15, ty = tid >> 4;

    // inline weight norm: 8 half-waves, one row each
    {
        int grp = tid >> 5, l32 = tid & 31;
        float ss = 0.f;
        if (l32 < 27) {
            float a = hv[(size_t)(ocBase + grp) * 27 + l32];
            ss = a * a;
        }
#pragma unroll
        for (int m = 16; m > 0; m >>= 1) ss += __shfl_xor(ss, m);
        if (l32 == 0) s_scl[grp] = hg[ocBase + grp] / sqrtf(ss);
    }

    float acc[OCT][4];
#pragma unroll
    for (int oc = 0; oc < OCT; ++oc)
#pragma unroll
        for (int p = 0; p < 4; ++p) acc[oc][p] = 0.f;

    const float* inb = in + (size_t)b * IC * 4096;
    for (int ic = 0; ic < IC; ++ic) {
        const float* src = inb + (size_t)ic * 4096;
        for (int i = tid; i < 34 * 34; i += 256) {
            int r = i / 34, cc = i % 34;
            int gy = ty0 + r - 1, gx = tx0 + cc - 1;
            float val = 0.f;
            if (gy >= 0 && gy < 64 && gx >= 0 && gx < 64) val = src[gy * 64 + gx] - 0.5f;
            s_in[i] = val;
        }
        __syncthreads();   // s_scl ready (first iter) + s_in ready
        for (int i = tid; i < OCT * 9; i += 256) {
            int oc = i / 9, t = i % 9;
            s_w[i] = hv[((size_t)(ocBase + oc) * IC + ic) * 9 + t] * s_scl[oc];
        }
        __syncthreads();
        float v[4][4];
#pragma unroll
        for (int r = 0; r < 4; ++r)
#pragma unroll
            for (int cc = 0; cc < 4; ++cc) v[r][cc] = s_in[(2 * ty + r) * 34 + (2 * tx + cc)];
#pragma unroll
        for (int oc = 0; oc < OCT; ++oc) {
#pragma unroll
            for (int ky = 0; ky < 3; ++ky)
#pragma unroll
                for (int kx = 0; kx < 3; ++kx) {
                    float wv = s_w[oc * 9 + ky * 3 + kx];
                    acc[oc][0] += wv * v[ky][kx];
                    acc[oc][1] += wv * v[ky][kx + 1];
                    acc[oc][2] += wv * v[ky + 1][kx];
                    acc[oc][3] += wv * v[ky + 1][kx + 1];
                }
        }
        __syncthreads();
    }
    int py = ty0 + 2 * ty, px = tx0 + 2 * tx;
#pragma unroll
    for (int oc = 0; oc < OCT; ++oc) {
        int og = ocBase + oc;
        float bv = bias[og];
        float osum = 0.f;
#pragma unroll
        for (int p = 0; p < 4; ++p) {
            int dy = p >> 1, dx = p & 1;
            float val = acc[oc][p] + bv;
            osum += val;
            out_bf[((size_t)(b * 2 + (og >> 5)) * 4356 + (py + dy + 1) * 66 + (px + dx + 1)) * 32
                   + (og & 31)] = bf16u(val);
        }
        for (int m = 1; m < 64; m <<= 1) osum += __shfl_xor(osum, m);
        if (lane == 0) wred[wid][oc] = osum;
    }
    __syncthreads();
    if (tid < OCT)
        atomicAdd(&hsum0[b * 64 + ocBase + tid],
                  wred[0][tid] + wred[1][tid] + wred[2][tid] + wred[3][tid]);
}

// ---------------------------------------------------------------------------
// Pixel shuffle + fused 5x5 skip conv (wn inline) + IMAGE_MEAN. [8,3,128,128]
// ---------------------------------------------------------------------------
__global__ __launch_bounds__(256) void shuffle_skip(
    const float* __restrict__ body, const float* __restrict__ x,
    const float* __restrict__ skv, const float* __restrict__ skg,
    const float* __restrict__ skb, float* __restrict__ out) {
    __shared__ float w[900];
    __shared__ float bb[12];
    __shared__ float scl[12];
    int tid = threadIdx.x;
    if (tid < 12) {
        float ss = 0.f;
        for (int j = 0; j < 75; ++j) { float a = skv[tid * 75 + j]; ss += a * a; }
        scl[tid] = skg[tid] / sqrtf(ss);
        bb[tid] = skb[tid];
    }
    __syncthreads();
    for (int i = tid; i < 900; i += 256) w[i] = skv[i] * scl[i / 75];
    __syncthreads();
    int idx = blockIdx.x * 256 + tid;
    int ox = idx & 127;
    int oy = (idx >> 7) & 127;
    int v = idx >> 14;
    int c = v % 3;
    int b = v / 3;
    int rx = ox & 1, ry = oy & 1;
    int xx = ox >> 1, yy = oy >> 1;
    int ch = c * 4 + ry * 2 + rx;
    float acc = bb[ch];
    for (int ic = 0; ic < 3; ++ic)
        for (int ky = 0; ky < 5; ++ky) {
            int gy = yy + ky - 2;
            if (gy < 0 || gy >= 64) continue;
            for (int kx = 0; kx < 5; ++kx) {
                int gx = xx + kx - 2;
                if (gx < 0 || gx >= 64) continue;
                acc += w[((ch * 3 + ic) * 5 + ky) * 5 + kx] *
                       (x[((size_t)(b * 3 + ic) * 64 + gy) * 64 + gx] - 0.5f);
            }
        }
    size_t src = (((size_t)b * 12 + ch) * 64 + yy) * 64 + xx;
    out[idx] = body[src] + acc + 0.5f;
}

// ---------------------------------------------------------------------------
extern "C" void kernel_launch(void* const* d_in, const int* in_sizes, int n_in,
                              void* d_out, int out_size, void* d_ws, size_t ws_size,
                              hipStream_t stream) {
    const float* x      = (const float*)d_in[0];
    const float* head_v = (const float*)d_in[1];
    const float* head_g = (const float*)d_in[2];
    const float* head_b = (const float*)d_in[3];
    const float* b1_v   = (const float*)d_in[4];
    const float* b1_g   = (const float*)d_in[5];
    const float* b1_b   = (const float*)d_in[6];
    const float* b1_mw  = (const float*)d_in[7];
    const float* b1_mb  = (const float*)d_in[8];
    const float* b2_v   = (const float*)d_in[9];
    const float* b2_g   = (const float*)d_in[10];
    const float* b2_b   = (const float*)d_in[11];
    const float* b2_mw  = (const float*)d_in[12];
    const float* b2_mb  = (const float*)d_in[13];
    const float* tail_v = (const float*)d_in[14];
    const float* tail_g = (const float*)d_in[15];
    const float* tail_b = (const float*)d_in[16];
    const float* skip_v = (const float*)d_in[17];
    const float* skip_g = (const float*)d_in[18];
    const float* skip_b = (const float*)d_in[19];

    float* ws = (float*)d_ws;
    size_t off = 0;
    auto alloc = [&](size_t n) { float* p = ws + off; off += (n + 3) & ~(size_t)3; return p; };
    float* sums   = alloc(10240);   // hsum[4] @ l*512 ; tsum[4] @ 2048 + l*2048
    float* sbuf   = alloc(64);
    float* body   = alloc((size_t)8 * 12 * 4096);
    unsigned short* wq1  = (unsigned short*)alloc((size_t)8 * 256 * 576 / 2);
    unsigned short* wq2  = (unsigned short*)alloc((size_t)8 * 64 * 2304 / 2);
    unsigned short* wqt  = (unsigned short*)alloc(9216 / 2);
    unsigned short* h_bf = (unsigned short*)alloc((size_t)8 * 2 * 4356 * 32 / 2);
    unsigned short* t_bf = (unsigned short*)alloc((size_t)8 * 8 * 4356 * 32 / 2);
    (void)ws_size; (void)in_sizes; (void)n_in; (void)out_size;

    auto hsum = [&](int l) { return sums + l * 512; };
    auto tsum = [&](int l) { return sums + 2048 + l * 2048; };

    setup_kernel<<<351, 256, 0, stream>>>(h_bf, t_bf, sums, tail_v, tail_g, wqt);
    head_conv<<<dim3(4, 8, 8), 256, 0, stream>>>(x, head_v, head_g, head_b, h_bf, hsum(0));

    for (int l = 0; l < 4; ++l) {
        // dyn conv 1: 64 -> 256, relu. WM=2/WN=2/NR=2, 1024 blocks, 4/CU.
        combine_v4<64, 4, 6><<<dim3(64, 8), 256, 0, stream>>>(
            b1_v + (size_t)l * 512 * 576, b1_g + (size_t)l * 512, hsum(l),
            b1_mw + (size_t)l * 8 * 64, b1_mb + l * 8, sbuf, wq1, 64, 256);
        conv_mfma<64, 256, 64, 2, 2, 2, true, false, false, true, 256, true, 4>
            <<<dim3(8, 32, 4), 256, 0, stream>>>(h_bf, wq1, b1_b + (size_t)l * 512, sbuf, 6,
                                                 nullptr, t_bf, tsum(l), 147456);
        // dyn conv 2: 256 -> 64, bf16 in-place residual. WM=4/WN=2/NR=1, 512thr.
        combine_v4<256, 2, 6><<<dim3(32, 8), 256, 0, stream>>>(
            b2_v + (size_t)l * 128 * 2304, b2_g + (size_t)l * 128, tsum(l),
            b2_mw + (size_t)l * 8 * 256, b2_mb + l * 8, sbuf, wq2, 16, 64);
        conv_mfma<256, 64, 64, 4, 2, 1, false, true, false, true, 64, true, 4>
            <<<dim3(8, 64, 1), 512, 0, stream>>>(t_bf, wq2, b2_b + (size_t)l * 128, sbuf, 4,
                                                 nullptr, h_bf, (l < 3) ? hsum(l + 1) : nullptr,
                                                 147456);
    }

    // tail: 64 -> 12 via MFMA (padded to 16), fp32 body out. NR=2, 256 blocks.
    conv_mfma<64, 16, 16, 1, 4, 2, false, false, true, false, 12, false, 2>
        <<<dim3(8, 32, 1), 256, 0, stream>>>(h_bf, wqt, tail_b, nullptr, 0,
                                             body, nullptr, nullptr, 0);
    // pixel shuffle + fused skip conv (wn inline)
    shuffle_skip<<<1536, 256, 0, stream>>>(body, x, skip_v, skip_g, skip_b, (float*)d_out);
}